// Round 2
// baseline (62654.352 us; speedup 1.0000x reference)
//
#include <hip/hip_runtime.h>
#include <hip/hip_fp16.h>
#include <math.h>

#define HD   512
#define BB   256
#define TT   200
#define DIN  64
#define DOUT 64
#define NCLS 10
#define LIPC 0.909f
#define PSTR 516            // padded partial-row stride (bank-spread across groups)

// d_ws layout: gs | W2 (pair-packed half2) | exchange buf | flags
#define GS_BYTES    407552
#define OFF2_WX     0              // 32 kp x 512
#define OFF2_WEMB   16384          // 512 kp x 512
#define OFF2_WF1    278528         // 256 kp x 512
#define OFF2_WF2    409600
#define OFF2_WOUT   540672
#define OFF2_WDEC   671744         // 256 kp x 64
#define NPACK       688128
#define EX_OFF      (GS_BYTES + NPACK * 4)                 // 3160064
#define EX_BYTES    (256 * 2 * 512 * 8)                    // 256 blocks x 2 slots x 512 float2
#define FLAG_OFF    (EX_OFF + EX_BYTES)

__device__ __forceinline__ float lipswish(float x) {
    return LIPC * x / (1.0f + expf(-x));
}

typedef _Float16 h2_t __attribute__((ext_vector_type(2)));

__device__ __forceinline__ float fdot2u(unsigned a, unsigned b, float c) {
    return __builtin_amdgcn_fdot2(__builtin_bit_cast(h2_t, a),
                                  __builtin_bit_cast(h2_t, b), c, false);
}

// thread j holds (row0,row1) values for col j; even lanes write half2 pairs
// (cols j, j+1) into layout dst[kp*2 + r], kp = j>>1.
__device__ __forceinline__ void pack2(float v0, float v1, unsigned* dstH, int j) {
    float o0 = __shfl_xor(v0, 1, 64);
    float o1 = __shfl_xor(v1, 1, 64);
    if (!(j & 1)) {
        dstH[((j >> 1) << 1) + 0] = __builtin_bit_cast(unsigned, __floats2half2_rn(v0, o0));
        dstH[((j >> 1) << 1) + 1] = __builtin_bit_cast(unsigned, __floats2half2_rn(v1, o1));
    }
}

// ---------------------------------------------------------------------------
// cvt: fp32 weights -> pair-packed half2; also zeroes the exchange flags.
// ---------------------------------------------------------------------------
__global__ __launch_bounds__(512) void cvt_kernel(
    const float* __restrict__ W_X,  const float* __restrict__ W_emb,
    const float* __restrict__ Wf1,  const float* __restrict__ Wf2,
    const float* __restrict__ W_out, const float* __restrict__ W_dec,
    unsigned* __restrict__ dst, int* __restrict__ flags)
{
    int bid = blockIdx.x;
    if (bid == 0 && threadIdx.x < 256) flags[threadIdx.x] = 0;
    size_t e = ((size_t)bid << 9) + threadIdx.x;
    const float* src; size_t off2; int csh;
    if      (bid < 32)   { src = W_X;   off2 = OFF2_WX;   csh = 9; }
    else if (bid < 544)  { src = W_emb; off2 = OFF2_WEMB; csh = 9; }
    else if (bid < 800)  { src = Wf1;   off2 = OFF2_WF1;  csh = 9; }
    else if (bid < 1056) { src = Wf2;   off2 = OFF2_WF2;  csh = 9; }
    else if (bid < 1312) { src = W_out; off2 = OFF2_WOUT; csh = 9; }
    else                 { src = W_dec; off2 = OFF2_WDEC; csh = 6; }
    size_t e2 = e - off2;
    size_t kp = e2 >> csh;
    size_t c  = e2 & (((size_t)1 << csh) - 1);
    size_t C  = (size_t)1 << csh;
    __half2 hp = __floats2half2_rn(src[(2 * kp) * C + c], src[(2 * kp + 1) * C + c]);
    dst[e] = __builtin_bit_cast(unsigned, hp);
}

// ---------------------------------------------------------------------------
// fp32 partial matvec for g_kernel (unchanged)
// ---------------------------------------------------------------------------
template<int K>
__device__ __forceinline__ void mv_part(const float* __restrict__ W,
                                        const float* src, float* part, int j)
{
    const int g = j >> 7, c = j & 127;
    const int kpg = K >> 2;
    const int k0 = g * kpg;
    const float4* __restrict__ W4 = (const float4*)W;
    float4 acc; acc.x = acc.y = acc.z = acc.w = 0.f;
#pragma unroll 2
    for (int k = k0; k < k0 + kpg; k += 4) {
        float4 a  = *(const float4*)(src + k);
        float4 w0 = W4[(size_t)(k + 0) * 128 + c];
        float4 w1 = W4[(size_t)(k + 1) * 128 + c];
        float4 w2 = W4[(size_t)(k + 2) * 128 + c];
        float4 w3 = W4[(size_t)(k + 3) * 128 + c];
        acc.x = fmaf(a.x, w0.x, acc.x); acc.y = fmaf(a.x, w0.y, acc.y);
        acc.z = fmaf(a.x, w0.z, acc.z); acc.w = fmaf(a.x, w0.w, acc.w);
        acc.x = fmaf(a.y, w1.x, acc.x); acc.y = fmaf(a.y, w1.y, acc.y);
        acc.z = fmaf(a.y, w1.z, acc.z); acc.w = fmaf(a.y, w1.w, acc.w);
        acc.x = fmaf(a.z, w2.x, acc.x); acc.y = fmaf(a.z, w2.y, acc.y);
        acc.z = fmaf(a.z, w2.z, acc.z); acc.w = fmaf(a.z, w2.w, acc.w);
        acc.x = fmaf(a.w, w3.x, acc.x); acc.y = fmaf(a.w, w3.y, acc.y);
        acc.z = fmaf(a.w, w3.z, acc.z); acc.w = fmaf(a.w, w3.w, acc.w);
    }
    *(float4*)(part + g * HD + 4 * c) = acc;
}
#define MV_REDUCE4(bias, j) ((bias)[j] + part[j] + part[HD + (j)] + part[2 * HD + (j)] + part[3 * HD + (j)])

__global__ __launch_bounds__(512) void g_kernel(
    const float* __restrict__ times, const float* __restrict__ W_noise,
    const float* __restrict__ b_noise, const float* __restrict__ Wg1,
    const float* __restrict__ bg1, const float* __restrict__ Wg2,
    const float* __restrict__ bg2, float* __restrict__ gs)
{
    int t = blockIdx.x;
    int j = threadIdx.x;
    __shared__ float tt[HD];
    __shared__ float h[HD];
    __shared__ float part[4 * HD];
    float tv = times[t];
    tt[j] = tv * W_noise[j] + b_noise[j];
    __syncthreads();
    mv_part<HD>(Wg1, tt, part, j);
    __syncthreads();
    h[j] = lipswish(MV_REDUCE4(bg1, j));
    __syncthreads();
    mv_part<HD>(Wg2, h, part, j);
    __syncthreads();
    float dt = times[t + 1] - times[t];
    gs[t * HD + j] = MV_REDUCE4(bg2, j) * sqrtf(dt);
}

// ---------------------------------------------------------------------------
// 2-row dot2 partial matvec over KPH kp's (this block's k-slice).
// 4 k-groups (g=j>>7) x 128 col-quads. Per kp: 1 ds_read_b64 (2 rows' act,
// wave-broadcast) + 1 dwordx4 (4 half2 weight cols) + 8 fdot2 = 32 MACs.
// ---------------------------------------------------------------------------
template<int KPH>
__device__ __forceinline__ void mv2(const unsigned* __restrict__ W2,  // pre-offset, stride 512
                                    const unsigned* actH,             // pre-offset, [kp*2+r]
                                    float* part, int j)
{
    const int g  = j >> 7;
    const int c4 = (j & 127) << 2;
    constexpr int kpg = KPH / 4;
    const int kp0 = g * kpg;
    float a00 = 0.f, a01 = 0.f, a02 = 0.f, a03 = 0.f;
    float a10 = 0.f, a11 = 0.f, a12 = 0.f, a13 = 0.f;
#pragma unroll 8
    for (int kp = kp0; kp < kp0 + kpg; ++kp) {
        uint2 ap = *(const uint2*)(actH + (kp << 1));
        uint4 w  = *(const uint4*)(W2 + ((size_t)kp << 9) + c4);
        a00 = fdot2u(ap.x, w.x, a00); a01 = fdot2u(ap.x, w.y, a01);
        a02 = fdot2u(ap.x, w.z, a02); a03 = fdot2u(ap.x, w.w, a03);
        a10 = fdot2u(ap.y, w.x, a10); a11 = fdot2u(ap.y, w.y, a11);
        a12 = fdot2u(ap.y, w.z, a12); a13 = fdot2u(ap.y, w.w, a13);
    }
    *(float4*)(part + (g * 2 + 0) * PSTR + c4) = make_float4(a00, a01, a02, a03);
    *(float4*)(part + (g * 2 + 1) * PSTR + c4) = make_float4(a10, a11, a12, a13);
}

// local 4-group reduce + cross-block partial exchange (double-buffered slot
// by seq parity; release/acquire flag handshake). Returns (row0,row1) sums.
__device__ __forceinline__ float2 xreduce(const float* part,
    float2* __restrict__ ex_mine, const float2* __restrict__ ex_peer,
    int* __restrict__ flag_mine, const int* __restrict__ flag_peer,
    int seq, int j)
{
    float l0 = (part[0 * PSTR + j] + part[2 * PSTR + j]) + (part[4 * PSTR + j] + part[6 * PSTR + j]);
    float l1 = (part[1 * PSTR + j] + part[3 * PSTR + j]) + (part[5 * PSTR + j] + part[7 * PSTR + j]);
    float2* slot = ex_mine + (size_t)(seq & 1) * 512;
    slot[j] = make_float2(l0, l1);
    __threadfence();
    __syncthreads();
    if (j == 0) {
        __hip_atomic_fetch_add(flag_mine, 1, __ATOMIC_RELEASE, __HIP_MEMORY_SCOPE_AGENT);
        while (__hip_atomic_load(flag_peer, __ATOMIC_ACQUIRE, __HIP_MEMORY_SCOPE_AGENT) < seq) {
            __builtin_amdgcn_s_sleep(1);
        }
    }
    __syncthreads();
    __threadfence();
    float2 pv = ex_peer[(size_t)(seq & 1) * 512 + j];
    return make_float2(l0 + pv.x, l1 + pv.y);
}

// decode one row (512 -> 64): 8 k-groups x 64 cols, full W_dec.
__device__ __forceinline__ void dec1(const unsigned* __restrict__ Wd2,
    const float* __restrict__ b_dec, const unsigned* yH, int r, float* dpart,
    int j, float* __restrict__ outp)
{
    const int g = j >> 6, c = j & 63;
    float acc = 0.f;
#pragma unroll 8
    for (int kp = g * 32; kp < g * 32 + 32; ++kp)
        acc = fdot2u(yH[(kp << 1) + r], Wd2[(kp << 6) + c], acc);
    dpart[g * 68 + c] = acc;
    __syncthreads();
    if (j < DOUT) {
        float s = b_dec[j];
#pragma unroll
        for (int g2 = 0; g2 < 8; ++g2) s += dpart[g2 * 68 + j];
        outp[j] = s;
    }
}

// ---------------------------------------------------------------------------
// Pair-split SDE scan: 128 pairs x 2 half-blocks = 256 blocks x 512 threads.
// Pair p = blocks {p, p+128} (same XCD mod 8). Each pair advances rows
// {2p, 2p+1}; half h streams only its k-half of each weight matrix and the
// halves exchange fp32 partials through L2 (4 syncs/step). Both halves keep
// identical full activations (commutative fp32 combine) -> no divergence.
// ---------------------------------------------------------------------------
__global__ __launch_bounds__(512) void scan_kernel(
    const float* __restrict__ coeffs,
    const float* __restrict__ times,
    const float* __restrict__ noise,
    const float* __restrict__ b_X,
    const float* __restrict__ b_emb,
    const float* __restrict__ bf1,
    const float* __restrict__ bf2,
    const float* __restrict__ b_out,
    const float* __restrict__ W_init, const float* __restrict__ b_init,
    const float* __restrict__ b_dec,
    const float* __restrict__ W_cls, const float* __restrict__ b_cls,
    const int* __restrict__ mask,
    const float* __restrict__ gs,
    const unsigned* __restrict__ W2,
    float2* __restrict__ exbuf,
    int* __restrict__ flags,
    float* __restrict__ out)
{
    const int bid = blockIdx.x;
    const int h   = bid >> 7;         // half id: 0 or 1
    const int p   = bid & 127;        // pair id
    const int b0  = p * 2;            // first batch row of the pair
    const int j   = threadIdx.x;

    float2* ex_mine       = exbuf + (size_t)(p * 2 + h) * 1024;
    const float2* ex_peer = exbuf + (size_t)(p * 2 + (1 - h)) * 1024;
    int* flag_mine        = flags + p * 2 + h;
    const int* flag_peer  = flags + p * 2 + (1 - h);

    const unsigned* __restrict__ W_X_2   = W2 + OFF2_WX;
    const unsigned* __restrict__ W_emb_2 = W2 + OFF2_WEMB;
    const unsigned* __restrict__ Wf1_2   = W2 + OFF2_WF1;
    const unsigned* __restrict__ Wf2_2   = W2 + OFF2_WF2;
    const unsigned* __restrict__ W_out_2 = W2 + OFF2_WOUT;
    const unsigned* __restrict__ W_dec_2 = W2 + OFF2_WDEC;

    __shared__ __align__(16) float    yF[2 * HD];          // fp32 Euler state, 2 rows
    __shared__ __align__(16) unsigned catH[2 * HD];        // [kp*2+r]: y kp<256 | xw kp>=256
    __shared__ __align__(16) unsigned actAH[HD];           // 256 kp x 2 rows
    __shared__ __align__(16) unsigned actBH[HD];
    __shared__ __align__(16) unsigned avecH[DIN];          // 32 kp x 2 rows
    __shared__ __align__(16) float    avecF[2 * DIN];      // [k*2+r]
    __shared__ __align__(16) float    part[8 * PSTR];      // 16.1 KB partials
    __shared__ __align__(16) float    zfin[HD];            // final y of row b0+h
    __shared__ float    tl[TT];
    __shared__ int      lidx_s[2];

    if (j < TT) tl[j] = times[j];

    // ---- per-row lengths from mask ----
    {
        int r = j >> 8, i = j & 255;
        int m = 0;
        for (int t2 = i; t2 < TT; t2 += 256) m += mask[(b0 + r) * TT + t2];
        part[j] = (float)m;
        __syncthreads();
        for (int s = 128; s > 0; s >>= 1) {
            if (i < s) part[j] += part[j + s];
            __syncthreads();
        }
        if (i == 0) lidx_s[r] = (int)part[r << 8] - 1;
        __syncthreads();
    }
    const int lidxh = lidx_s[h];

    // ---- y0 = a0 @ W_init + b_init (fp32, redundant in both halves) ----
    if (j < 2 * DIN) {
        int k = j >> 1, r = j & 1;
        avecF[(k << 1) + r] = coeffs[(size_t)(b0 + r) * (TT - 1) * (4 * DIN) + k];
    }
    __syncthreads();
    {
        float acc0 = 0.f, acc1 = 0.f;
#pragma unroll 8
        for (int k = 0; k < DIN; ++k) {
            float2 a2 = *(const float2*)(avecF + (k << 1));
            float w = W_init[(size_t)k * HD + j];
            acc0 = fmaf(a2.x, w, acc0);
            acc1 = fmaf(a2.y, w, acc1);
        }
        float bi = b_init[j];
        float v0 = acc0 + bi, v1 = acc1 + bi;
        yF[j] = v0; yF[HD + j] = v1;
        pack2(v0, v1, catH, j);
        if (lidxh == 0) zfin[j] = h ? v1 : v0;
    }
    __syncthreads();

    // ---- decode y0 for my row ----
    dec1(W_dec_2, b_dec, catH, h, part, j, out + (size_t)(b0 + h) * TT * DOUT);

    // ---- main scan ----
    int seq = 1;
    for (int t = 0; t < TT - 1; ++t) {
        // xw = a_t @ W_X + b_X : only half 1 needs it (its W_emb slice is xw)
        if (h) {
            if (j < DIN) {
                int r = j & 1, kp = j >> 1;
                float2 a2 = *(const float2*)(coeffs +
                    ((size_t)(b0 + r) * (TT - 1) + t) * (4 * DIN) + 2 * kp);
                avecH[(kp << 1) + r] = __builtin_bit_cast(unsigned, __floats2half2_rn(a2.x, a2.y));
            }
            __syncthreads();
            mv2<32>(W_X_2, avecH, part, j);
            __syncthreads();
            {
                float l0 = (part[0 * PSTR + j] + part[2 * PSTR + j]) + (part[4 * PSTR + j] + part[6 * PSTR + j]);
                float l1 = (part[1 * PSTR + j] + part[3 * PSTR + j]) + (part[5 * PSTR + j] + part[7 * PSTR + j]);
                float bb = b_X[j];
                pack2(l0 + bb, l1 + bb, catH + 512, j);
            }
        }
        __syncthreads();
        // z1 = [y,xw] @ W_emb + b_emb (k-split: h0 = y half, h1 = xw half)
        mv2<256>(W_emb_2 + (size_t)h * 256 * 512, catH + h * 512, part, j);
        __syncthreads();
        {
            float2 s = xreduce(part, ex_mine, ex_peer, flag_mine, flag_peer, seq, j); ++seq;
            float bb = b_emb[j];
            pack2(s.x + bb, s.y + bb, actAH, j);
        }
        __syncthreads();
        // z2 = lipswish(z1 @ Wf1 + bf1)
        mv2<128>(Wf1_2 + (size_t)h * 128 * 512, actAH + h * 256, part, j);
        __syncthreads();
        {
            float2 s = xreduce(part, ex_mine, ex_peer, flag_mine, flag_peer, seq, j); ++seq;
            float bb = bf1[j];
            pack2(lipswish(s.x + bb), lipswish(s.y + bb), actBH, j);
        }
        __syncthreads();
        // z3 = z2 @ Wf2 + bf2
        mv2<128>(Wf2_2 + (size_t)h * 128 * 512, actBH + h * 256, part, j);
        __syncthreads();
        {
            float2 s = xreduce(part, ex_mine, ex_peer, flag_mine, flag_peer, seq, j); ++seq;
            float bb = bf2[j];
            pack2(s.x + bb, s.y + bb, actAH, j);
        }
        __syncthreads();
        // drift = z3 @ W_out + b_out; Euler update
        mv2<128>(W_out_2 + (size_t)h * 128 * 512, actAH + h * 256, part, j);
        __syncthreads();
        {
            float2 s = xreduce(part, ex_mine, ex_peer, flag_mine, flag_peer, seq, j); ++seq;
            float bb = b_out[j];
            float dtv = tl[t + 1] - tl[t];
            float gv  = gs[(size_t)t * HD + j];
            float y0n = yF[j]      + (s.x + bb) * dtv + gv * noise[((size_t)t * BB + b0    ) * HD + j];
            float y1n = yF[HD + j] + (s.y + bb) * dtv + gv * noise[((size_t)t * BB + b0 + 1) * HD + j];
            yF[j] = y0n; yF[HD + j] = y1n;
            pack2(y0n, y1n, catH, j);
            if (t + 1 == lidxh) zfin[j] = h ? y1n : y0n;
        }
        __syncthreads();
        // decode y_{t+1} for my row
        dec1(W_dec_2, b_dec, catH, h, part, j,
             out + ((size_t)(b0 + h) * TT + t + 1) * DOUT);
    }
    __syncthreads();

    // ---- logits for row b0+h ----
    {
        int c = j & 15, seg = j >> 4;
        float pacc = 0.f;
        if (c < NCLS) {
#pragma unroll
            for (int k = seg * 16; k < seg * 16 + 16; ++k)
                pacc = fmaf(zfin[k], W_cls[k * NCLS + c], pacc);
        }
        part[j] = pacc;
        __syncthreads();
        if (j < NCLS) {
            float s = b_cls[j];
#pragma unroll
            for (int sg = 0; sg < 32; ++sg) s += part[sg * 16 + j];
            out[(size_t)BB * TT * DOUT + (size_t)(b0 + h) * NCLS + j] = s;
        }
    }
}

extern "C" void kernel_launch(void* const* d_in, const int* in_sizes, int n_in,
                              void* d_out, int out_size, void* d_ws, size_t ws_size,
                              hipStream_t stream)
{
    const float* coeffs  = (const float*)d_in[0];
    const float* times   = (const float*)d_in[1];
    const float* noise   = (const float*)d_in[2];
    const float* W_X     = (const float*)d_in[3];
    const float* b_X     = (const float*)d_in[4];
    const float* W_emb   = (const float*)d_in[5];
    const float* b_emb   = (const float*)d_in[6];
    const float* Wf1     = (const float*)d_in[7];
    const float* bf1     = (const float*)d_in[8];
    const float* Wf2     = (const float*)d_in[9];
    const float* bf2     = (const float*)d_in[10];
    const float* W_out   = (const float*)d_in[11];
    const float* b_out   = (const float*)d_in[12];
    const float* W_noise = (const float*)d_in[13];
    const float* b_noise = (const float*)d_in[14];
    const float* Wg1     = (const float*)d_in[15];
    const float* bg1     = (const float*)d_in[16];
    const float* Wg2     = (const float*)d_in[17];
    const float* bg2     = (const float*)d_in[18];
    const float* W_init  = (const float*)d_in[19];
    const float* b_init  = (const float*)d_in[20];
    const float* W_dec   = (const float*)d_in[21];
    const float* b_dec   = (const float*)d_in[22];
    const float* W_cls   = (const float*)d_in[23];
    const float* b_cls   = (const float*)d_in[24];
    const int*   mask    = (const int*)d_in[25];

    float*    gs    = (float*)d_ws;
    unsigned* W2    = (unsigned*)((char*)d_ws + GS_BYTES);
    float2*   exbuf = (float2*)((char*)d_ws + EX_OFF);
    int*      flags = (int*)((char*)d_ws + FLAG_OFF);
    float*    out   = (float*)d_out;

    cvt_kernel<<<dim3(NPACK / 512), dim3(512), 0, stream>>>(
        W_X, W_emb, Wf1, Wf2, W_out, W_dec, W2, flags);

    g_kernel<<<dim3(TT - 1), dim3(HD), 0, stream>>>(
        times, W_noise, b_noise, Wg1, bg1, Wg2, bg2, gs);

    scan_kernel<<<dim3(BB), dim3(512), 0, stream>>>(
        coeffs, times, noise, b_X, b_emb, bf1, bf2, b_out,
        W_init, b_init, b_dec, W_cls, b_cls, mask, gs, W2, exbuf, flags, out);
}

// Round 3
// 4776.731 us; speedup vs baseline: 13.1166x; 13.1166x over previous
//
#include <hip/hip_runtime.h>
#include <hip/hip_fp16.h>
#include <math.h>

#define HD   512
#define BB   256
#define TT   200
#define DIN  64
#define DOUT 64
#define NCLS 10
#define LIPC 0.909f

// d_ws layout: gs (fp32) | W2 pair-packed half2 | WfuP (32 kp x 512) | bias1 (512 f32)
// W2[kp][col] = (W[2kp][col], W[2kp+1][col]) as one uint (half2).
#define GS_BYTES    407552
#define OFF2_WX     0              // 32 kp x 512 (kept for layout compat; unused in scan)
#define OFF2_WEMB   16384          // 512 kp x 512 (scan streams only first 256 kp = We_y)
#define OFF2_WF1    278528         // 256 kp x 512
#define OFF2_WF2    409600
#define OFF2_WOUT   540672
#define OFF2_WDEC   671744         // 256 kp x 64
#define NPACK       688128         // total uints in W2
#define NFU         16384          // WfuP uints (32 kp x 512)

__device__ __forceinline__ float lipswish(float x) {
    return LIPC * x / (1.0f + expf(-x));
}

typedef _Float16 h2_t __attribute__((ext_vector_type(2)));

__device__ __forceinline__ float fdot2u(unsigned a, unsigned b, float c) {
    return __builtin_amdgcn_fdot2(__builtin_bit_cast(h2_t, a),
                                  __builtin_bit_cast(h2_t, b), c, false);
}

// pack adjacent-column fp32 activations into half2 LDS once per layer:
// thread j holds v for col j; even lanes write pair (j, j+1).
__device__ __forceinline__ void pack_store(float v, unsigned* dstH, int j) {
    float other = __shfl_xor(v, 1, 64);
    if ((j & 1) == 0) {
        __half2 hp = __floats2half2_rn(v, other);
        dstH[j >> 1] = __builtin_bit_cast(unsigned, hp);
    }
}

// ---------------------------------------------------------------------------
// cvt: fp32 weights -> pair-packed half2. 1344 blocks x 512.
// ---------------------------------------------------------------------------
__global__ __launch_bounds__(512) void cvt_kernel(
    const float* __restrict__ W_X,  const float* __restrict__ W_emb,
    const float* __restrict__ Wf1,  const float* __restrict__ Wf2,
    const float* __restrict__ W_out, const float* __restrict__ W_dec,
    unsigned* __restrict__ dst)
{
    int bid = blockIdx.x;
    size_t e = ((size_t)bid << 9) + threadIdx.x;
    const float* src; size_t off2; int csh;
    if      (bid < 32)   { src = W_X;   off2 = OFF2_WX;   csh = 9; }
    else if (bid < 544)  { src = W_emb; off2 = OFF2_WEMB; csh = 9; }
    else if (bid < 800)  { src = Wf1;   off2 = OFF2_WF1;  csh = 9; }
    else if (bid < 1056) { src = Wf2;   off2 = OFF2_WF2;  csh = 9; }
    else if (bid < 1312) { src = W_out; off2 = OFF2_WOUT; csh = 9; }
    else                 { src = W_dec; off2 = OFF2_WDEC; csh = 6; }
    size_t e2 = e - off2;
    size_t kp = e2 >> csh;
    size_t c  = e2 & (((size_t)1 << csh) - 1);
    size_t C  = (size_t)1 << csh;
    __half2 hp = __floats2half2_rn(src[(2 * kp) * C + c], src[(2 * kp + 1) * C + c]);
    dst[e] = __builtin_bit_cast(unsigned, hp);
}

// ---------------------------------------------------------------------------
// fuse: Wfu = W_X @ We_x (64x512, one fp16 rounding at the end) and
// bias1 = b_X @ We_x + b_emb (fp32). We_x = W_emb rows 512..1023.
// 33 blocks x 512 threads.
// ---------------------------------------------------------------------------
__global__ __launch_bounds__(512) void fuse_kernel(
    const float* __restrict__ W_X, const float* __restrict__ W_emb,
    const float* __restrict__ b_X, const float* __restrict__ b_emb,
    unsigned* __restrict__ WfuP, float* __restrict__ bias1)
{
    const int bid = blockIdx.x;
    const int j   = threadIdx.x;
    if (bid < 32) {
        const int k0 = bid * 2;
        float a0 = 0.f, a1 = 0.f;
#pragma unroll 4
        for (int n = 0; n < HD; ++n) {
            float w = W_emb[(size_t)(HD + n) * HD + j];
            a0 = fmaf(W_X[(size_t)k0 * HD + n],       w, a0);
            a1 = fmaf(W_X[(size_t)(k0 + 1) * HD + n], w, a1);
        }
        WfuP[(bid << 9) + j] = __builtin_bit_cast(unsigned, __floats2half2_rn(a0, a1));
    } else {
        float a0 = 0.f;
#pragma unroll 4
        for (int n = 0; n < HD; ++n)
            a0 = fmaf(b_X[n], W_emb[(size_t)(HD + n) * HD + j], a0);
        bias1[j] = a0 + b_emb[j];
    }
}

// ---------------------------------------------------------------------------
// fp32 partial matvec (g_kernel + one-time W_init): 4 k-groups x 128 f4-cols
// ---------------------------------------------------------------------------
template<int K>
__device__ __forceinline__ void mv_part(const float* __restrict__ W,
                                        const float* src, float* part, int j)
{
    const int g = j >> 7, c = j & 127;
    const int kpg = K >> 2;
    const int k0 = g * kpg;
    const float4* __restrict__ W4 = (const float4*)W;
    float4 acc; acc.x = acc.y = acc.z = acc.w = 0.f;
#pragma unroll 2
    for (int k = k0; k < k0 + kpg; k += 4) {
        float4 a  = *(const float4*)(src + k);
        float4 w0 = W4[(size_t)(k + 0) * 128 + c];
        float4 w1 = W4[(size_t)(k + 1) * 128 + c];
        float4 w2 = W4[(size_t)(k + 2) * 128 + c];
        float4 w3 = W4[(size_t)(k + 3) * 128 + c];
        acc.x = fmaf(a.x, w0.x, acc.x); acc.y = fmaf(a.x, w0.y, acc.y);
        acc.z = fmaf(a.x, w0.z, acc.z); acc.w = fmaf(a.x, w0.w, acc.w);
        acc.x = fmaf(a.y, w1.x, acc.x); acc.y = fmaf(a.y, w1.y, acc.y);
        acc.z = fmaf(a.y, w1.z, acc.z); acc.w = fmaf(a.y, w1.w, acc.w);
        acc.x = fmaf(a.z, w2.x, acc.x); acc.y = fmaf(a.z, w2.y, acc.y);
        acc.z = fmaf(a.z, w2.z, acc.z); acc.w = fmaf(a.z, w2.w, acc.w);
        acc.x = fmaf(a.w, w3.x, acc.x); acc.y = fmaf(a.w, w3.y, acc.y);
        acc.z = fmaf(a.w, w3.z, acc.z); acc.w = fmaf(a.w, w3.w, acc.w);
    }
    *(float4*)(part + g * HD + 4 * c) = acc;
}
#define MV_REDUCE4(bias, j) ((bias)[j] + part[j] + part[HD + (j)] + part[2 * HD + (j)] + part[3 * HD + (j)])
#define MV_REDUCE8(bias, j) ((bias)[j] + ((part[j] + part[HD + (j)]) + (part[2 * HD + (j)] + part[3 * HD + (j)])) \
                           + ((part[4 * HD + (j)] + part[5 * HD + (j)]) + (part[6 * HD + (j)] + part[7 * HD + (j)])))

__global__ __launch_bounds__(512) void g_kernel(
    const float* __restrict__ times, const float* __restrict__ W_noise,
    const float* __restrict__ b_noise, const float* __restrict__ Wg1,
    const float* __restrict__ bg1, const float* __restrict__ Wg2,
    const float* __restrict__ bg2, float* __restrict__ gs)
{
    int t = blockIdx.x;
    int j = threadIdx.x;
    __shared__ float tt[HD];
    __shared__ float h[HD];
    __shared__ float part[4 * HD];
    float tv = times[t];
    tt[j] = tv * W_noise[j] + b_noise[j];
    __syncthreads();
    mv_part<HD>(Wg1, tt, part, j);
    __syncthreads();
    h[j] = lipswish(MV_REDUCE4(bg1, j));
    __syncthreads();
    mv_part<HD>(Wg2, h, part, j);
    __syncthreads();
    float dt = times[t + 1] - times[t];
    gs[t * HD + j] = MV_REDUCE4(bg2, j) * sqrtf(dt);
}

// ---------------------------------------------------------------------------
// dot2 matvec, 512 output cols: 8 kp-groups (g=j>>6) x 64 col-octets.
// Per kp: 1 ds_read_b32 (act half2 broadcast) + 2 dwordx4 (8 half2 weights)
// + 8 v_dot2_f32_f16 => 16 MACs.
// ---------------------------------------------------------------------------
template<int KP>
__device__ __forceinline__ void mv_dot2(const unsigned* __restrict__ W2,
                                        const unsigned* actH, float* part, int j)
{
    const int g = j >> 6, o8 = (j & 63) << 3;
    constexpr int kpg = KP / 8;
    const int kp0 = g * kpg;
    float acc[8];
#pragma unroll
    for (int i = 0; i < 8; ++i) acc[i] = 0.f;
#pragma unroll 8
    for (int kp = kp0; kp < kp0 + kpg; ++kp) {
        unsigned ap = actH[kp];
        uint4 w0 = *(const uint4*)(W2 + ((size_t)kp << 9) + o8);
        uint4 w1 = *(const uint4*)(W2 + ((size_t)kp << 9) + o8 + 4);
        acc[0] = fdot2u(ap, w0.x, acc[0]);
        acc[1] = fdot2u(ap, w0.y, acc[1]);
        acc[2] = fdot2u(ap, w0.z, acc[2]);
        acc[3] = fdot2u(ap, w0.w, acc[3]);
        acc[4] = fdot2u(ap, w1.x, acc[4]);
        acc[5] = fdot2u(ap, w1.y, acc[5]);
        acc[6] = fdot2u(ap, w1.z, acc[6]);
        acc[7] = fdot2u(ap, w1.w, acc[7]);
    }
    float* pb = part + (g << 9) + o8;
    *(float4*)(pb)     = make_float4(acc[0], acc[1], acc[2], acc[3]);
    *(float4*)(pb + 4) = make_float4(acc[4], acc[5], acc[6], acc[7]);
}

// ---------------------------------------------------------------------------
// dot2 decode (512 -> 64) + store: 64 kp-groups (4 kp each) x 8 col-octets.
// ---------------------------------------------------------------------------
__device__ __forceinline__ void decode_store_d2(const unsigned* __restrict__ Wd2,
    const float* __restrict__ b_dec, const unsigned* yH, float* part, float* dscr,
    int j, float* __restrict__ outp)
{
    const int g = j >> 3, o8 = (j & 7) << 3;
    const int kp0 = g << 2;
    float acc[8];
#pragma unroll
    for (int i = 0; i < 8; ++i) acc[i] = 0.f;
#pragma unroll
    for (int kp = kp0; kp < kp0 + 4; ++kp) {
        unsigned ap = yH[kp];
        uint4 w0 = *(const uint4*)(Wd2 + ((size_t)kp << 6) + o8);
        uint4 w1 = *(const uint4*)(Wd2 + ((size_t)kp << 6) + o8 + 4);
        acc[0] = fdot2u(ap, w0.x, acc[0]);
        acc[1] = fdot2u(ap, w0.y, acc[1]);
        acc[2] = fdot2u(ap, w0.z, acc[2]);
        acc[3] = fdot2u(ap, w0.w, acc[3]);
        acc[4] = fdot2u(ap, w1.x, acc[4]);
        acc[5] = fdot2u(ap, w1.y, acc[5]);
        acc[6] = fdot2u(ap, w1.z, acc[6]);
        acc[7] = fdot2u(ap, w1.w, acc[7]);
    }
    float* pb = part + (g << 6) + o8;
    *(float4*)(pb)     = make_float4(acc[0], acc[1], acc[2], acc[3]);
    *(float4*)(pb + 4) = make_float4(acc[4], acc[5], acc[6], acc[7]);
    __syncthreads();
    {
        int o2 = j >> 6, col = j & 63;
        float s = 0.f;
#pragma unroll
        for (int i = 0; i < 8; ++i) s += part[((o2 << 3) + i) * 64 + col];
        dscr[(o2 << 6) + col] = s;
    }
    __syncthreads();
    if (j < DOUT) {
        float s = b_dec[j];
#pragma unroll
        for (int i = 0; i < 8; ++i) s += dscr[(i << 6) + j];
        outp[j] = s;
    }
}

// ---------------------------------------------------------------------------
// Batch-parallel SDE scan (round-0 structure) with the xw/We_x phase fused:
// z1 = y @ We_y + a @ Wfu + bias1, Wfu resident in LDS (64 KB, staged once).
// grid = B blocks x 512 threads, one block per batch row.
// ---------------------------------------------------------------------------
__global__ __launch_bounds__(512) void scan_kernel(
    const float* __restrict__ coeffs,
    const float* __restrict__ times,
    const float* __restrict__ noise,
    const float* __restrict__ bias1,
    const float* __restrict__ bf1,
    const float* __restrict__ bf2,
    const float* __restrict__ b_out,
    const float* __restrict__ W_init, const float* __restrict__ b_init,
    const float* __restrict__ b_dec,
    const float* __restrict__ W_cls, const float* __restrict__ b_cls,
    const int* __restrict__ mask,
    const float* __restrict__ gs,
    const unsigned* __restrict__ W2,    // pair-packed half2 weights
    const unsigned* __restrict__ WfuG,  // fused a-path weights (32 kp x 512)
    float* __restrict__ out)
{
    const int b = blockIdx.x;
    const int j = threadIdx.x;

    const unsigned* __restrict__ W_emb_2 = W2 + OFF2_WEMB;   // first 256 kp = We_y
    const unsigned* __restrict__ Wf1_2   = W2 + OFF2_WF1;
    const unsigned* __restrict__ Wf2_2   = W2 + OFF2_WF2;
    const unsigned* __restrict__ W_out_2 = W2 + OFF2_WOUT;
    const unsigned* __restrict__ W_dec_2 = W2 + OFF2_WDEC;

    __shared__ float    yF[HD];          // fp32 y (Euler state)
    __shared__ unsigned yH[HD / 2];      // y packed as half2 pairs
    __shared__ unsigned actAH[HD / 2];
    __shared__ unsigned actBH[HD / 2];
    __shared__ unsigned avecH[DIN / 2];
    __shared__ unsigned WfuL[32 * HD];   // 64 KB fused weight cache
    __shared__ float    part[8 * HD];    // 16 KB partials
    __shared__ float    dscr[HD];
    __shared__ float    avec[DIN];
    __shared__ float    zfin[HD];
    __shared__ float    tl[TT];
    __shared__ int      last_idx_s;

    if (j < TT) tl[j] = times[j];

    // ---- stage fused weights into LDS (one-time, coalesced) ----
#pragma unroll
    for (int i = 0; i < 32; ++i) WfuL[i * 512 + j] = WfuG[i * 512 + j];

    // ---- per-row length from mask ----
    {
        int m = 0;
        for (int t = j; t < TT; t += 512) m += mask[b * TT + t];
        part[j] = (float)m;
        __syncthreads();
        for (int s = 256; s > 0; s >>= 1) {
            if (j < s) part[j] += part[j + s];
            __syncthreads();
        }
        if (j == 0) last_idx_s = (int)part[0] - 1;
        __syncthreads();
    }
    const int last_idx = last_idx_s;

    // ---- y0 = a0 @ W_init + b_init (fp32, one-time) ----
    if (j < DIN / 4)
        ((float4*)avec)[j] = ((const float4*)(coeffs + (size_t)b * (TT - 1) * 4 * DIN))[j];
    __syncthreads();
    mv_part<DIN>(W_init, avec, part, j);
    __syncthreads();
    {
        float y = MV_REDUCE4(b_init, j);
        yF[j] = y;
        pack_store(y, yH, j);
        if (last_idx == 0) zfin[j] = y;
    }
    __syncthreads();

    // ---- decode y0 ----
    decode_store_d2(W_dec_2, b_dec, yH, part, dscr, j,
                    out + ((size_t)b * TT + 0) * DOUT);

    // ---- main scan ----
    for (int t = 0; t < TT - 1; ++t) {
        // a_t (first 64 of the 256-wide coeff row), packed to half2
        if (j < DIN / 2) {
            float2 a2 = ((const float2*)(coeffs + ((size_t)b * (TT - 1) + t) * 4 * DIN))[j];
            __half2 hp = __floats2half2_rn(a2.x, a2.y);
            avecH[j] = __builtin_bit_cast(unsigned, hp);
        }
        __syncthreads();   // also closes decode's dscr phase
        // z1 = y @ We_y (streamed) + a @ Wfu (LDS) + bias1 -> actAH
        mv_dot2<HD / 2>(W_emb_2, yH, part, j);
        __syncthreads();
        {
            float s = MV_REDUCE8(bias1, j);
#pragma unroll
            for (int kp = 0; kp < 32; ++kp)
                s = fdot2u(avecH[kp], WfuL[(kp << 9) + j], s);
            pack_store(s, actAH, j);
        }
        __syncthreads();
        // z2 = lipswish(z1 @ Wf1 + bf1) -> actBH
        mv_dot2<HD / 2>(Wf1_2, actAH, part, j);
        __syncthreads();
        pack_store(lipswish(MV_REDUCE8(bf1, j)), actBH, j);
        __syncthreads();
        // z3 = z2 @ Wf2 + bf2 -> actAH
        mv_dot2<HD / 2>(Wf2_2, actBH, part, j);
        __syncthreads();
        pack_store(MV_REDUCE8(bf2, j), actAH, j);
        __syncthreads();
        // drift = z3 @ W_out + b_out; Euler update -> yF, yH
        mv_dot2<HD / 2>(W_out_2, actAH, part, j);
        __syncthreads();
        {
            float dr = MV_REDUCE8(b_out, j);
            float dtv = tl[t + 1] - tl[t];
            float yn = yF[j] + dr * dtv
                     + gs[(size_t)t * HD + j] * noise[((size_t)t * BB + b) * HD + j];
            yF[j] = yn;
            pack_store(yn, yH, j);
            if (t + 1 == last_idx) zfin[j] = yn;
        }
        __syncthreads();
        // decode y_{t+1}
        decode_store_d2(W_dec_2, b_dec, yH, part, dscr, j,
                        out + ((size_t)b * TT + (t + 1)) * DOUT);
    }
    __syncthreads();

    // ---- logits (fp32, one-time) ----
    {
        int c = j & 15, seg = j >> 4;
        float p = 0.f;
        if (c < NCLS) {
#pragma unroll
            for (int k = seg * 16; k < seg * 16 + 16; ++k)
                p = fmaf(zfin[k], W_cls[k * NCLS + c], p);
        }
        part[j] = p;
        __syncthreads();
        if (j < NCLS) {
            float s = b_cls[j];
#pragma unroll
            for (int sg = 0; sg < 32; ++sg) s += part[sg * 16 + j];
            out[(size_t)BB * TT * DOUT + b * NCLS + j] = s;
        }
    }
}

extern "C" void kernel_launch(void* const* d_in, const int* in_sizes, int n_in,
                              void* d_out, int out_size, void* d_ws, size_t ws_size,
                              hipStream_t stream)
{
    const float* coeffs  = (const float*)d_in[0];
    const float* times   = (const float*)d_in[1];
    const float* noise   = (const float*)d_in[2];
    const float* W_X     = (const float*)d_in[3];
    const float* b_X     = (const float*)d_in[4];
    const float* W_emb   = (const float*)d_in[5];
    const float* b_emb   = (const float*)d_in[6];
    const float* Wf1     = (const float*)d_in[7];
    const float* bf1     = (const float*)d_in[8];
    const float* Wf2     = (const float*)d_in[9];
    const float* bf2     = (const float*)d_in[10];
    const float* W_out   = (const float*)d_in[11];
    const float* b_out   = (const float*)d_in[12];
    const float* W_noise = (const float*)d_in[13];
    const float* b_noise = (const float*)d_in[14];
    const float* Wg1     = (const float*)d_in[15];
    const float* bg1     = (const float*)d_in[16];
    const float* Wg2     = (const float*)d_in[17];
    const float* bg2     = (const float*)d_in[18];
    const float* W_init  = (const float*)d_in[19];
    const float* b_init  = (const float*)d_in[20];
    const float* W_dec   = (const float*)d_in[21];
    const float* b_dec   = (const float*)d_in[22];
    const float* W_cls   = (const float*)d_in[23];
    const float* b_cls   = (const float*)d_in[24];
    const int*   mask    = (const int*)d_in[25];

    float*    gs    = (float*)d_ws;
    unsigned* W2    = (unsigned*)((char*)d_ws + GS_BYTES);
    unsigned* WfuP  = W2 + NPACK;
    float*    bias1 = (float*)(W2 + NPACK + NFU);
    float*    out   = (float*)d_out;

    cvt_kernel<<<dim3(NPACK / 512), dim3(512), 0, stream>>>(
        W_X, W_emb, Wf1, Wf2, W_out, W_dec, W2);

    fuse_kernel<<<dim3(33), dim3(512), 0, stream>>>(
        W_X, W_emb, b_X, b_emb, WfuP, bias1);

    g_kernel<<<dim3(TT - 1), dim3(HD), 0, stream>>>(
        times, W_noise, b_noise, Wg1, bg1, Wg2, bg2, gs);

    scan_kernel<<<dim3(BB), dim3(512), 0, stream>>>(
        coeffs, times, noise, bias1, bf1, bf2, b_out,
        W_init, b_init, b_dec, W_cls, b_cls, mask, gs, W2, WfuP, out);
}

// Round 4
// 2136.845 us; speedup vs baseline: 29.3210x; 2.2354x over previous
//
#include <hip/hip_runtime.h>
#include <hip/hip_fp16.h>
#include <math.h>

#define HD   512
#define BB   256
#define TT   200
#define DIN  64
#define DOUT 64
#define NCLS 10
#define LIPC 0.909f

// ---------------- workspace layout (bytes) ----------------
#define GS_BYTES    407552
#define OFF2_WX     0
#define OFF2_WEMB   16384
#define OFF2_WF1    278528
#define OFF2_WF2    409600
#define OFF2_WOUT   540672
#define OFF2_WDEC   671744         // 256 kp x 64
#define NPACK       688128         // uints in W2
#define NFU         16384          // WfuP uints

// new-path extras (byte offsets from ws base)
#define OFF_GF      3227648ULL     // 512x512 f32
#define OFF_HF      4276224ULL
#define OFF_MF      5324800ULL
#define OFF_T64     6373376ULL     // 64x512 f32
#define OFF_F1F     6504448ULL
#define OFF_MDF     6635520ULL     // 512x64 f32
#define OFF_MCF     6766592ULL     // 512x16 f32
#define OFF_C1      6799360ULL
#define OFF_H0      6801408ULL
#define OFF_M0      6803456ULL
#define OFF_MD0     6805504ULL
#define OFF_MC0     6805760ULL
#define OFF_M2      6805824ULL     // 256x512 uint
#define OFF_G2      7330112ULL
#define OFF_F1P     7854400ULL     // 32x512 uint
#define OFF_MDP     7919936ULL     // 256x64 uint
#define OFF_MCP     7985472ULL     // 256x16 uint
#define OFF_WC16    8001856ULL     // 256x16 uint
#define OFF_E1H     8018240ULL     // 50944x512 half
#define OFF_EDF     60184896ULL    // 50944x64 f32
#define OFF_ECF     73226560ULL    // 50944x16 f32
#define WS_NEED     76486976ULL

__device__ __forceinline__ float lipswish(float x) {
    return LIPC * x / (1.0f + expf(-x));
}

typedef _Float16 h2_t __attribute__((ext_vector_type(2)));

__device__ __forceinline__ float fdot2u(unsigned a, unsigned b, float c) {
    return __builtin_amdgcn_fdot2(__builtin_bit_cast(h2_t, a),
                                  __builtin_bit_cast(h2_t, b), c, false);
}

__device__ __forceinline__ unsigned packh2(float a, float b) {
    __half2 hp = __floats2half2_rn(a, b);
    return __builtin_bit_cast(unsigned, hp);
}

__device__ __forceinline__ void pack_store(float v, unsigned* dstH, int j) {
    float other = __shfl_xor(v, 1, 64);
    if ((j & 1) == 0) dstH[j >> 1] = packh2(v, other);
}

// ---------------------------------------------------------------------------
// cvt: fp32 weights -> pair-packed half2 (W2). 1344 blocks x 512.
// ---------------------------------------------------------------------------
__global__ __launch_bounds__(512) void cvt_kernel(
    const float* __restrict__ W_X,  const float* __restrict__ W_emb,
    const float* __restrict__ Wf1,  const float* __restrict__ Wf2,
    const float* __restrict__ W_out, const float* __restrict__ W_dec,
    unsigned* __restrict__ dst)
{
    int bid = blockIdx.x;
    size_t e = ((size_t)bid << 9) + threadIdx.x;
    const float* src; size_t off2; int csh;
    if      (bid < 32)   { src = W_X;   off2 = OFF2_WX;   csh = 9; }
    else if (bid < 544)  { src = W_emb; off2 = OFF2_WEMB; csh = 9; }
    else if (bid < 800)  { src = Wf1;   off2 = OFF2_WF1;  csh = 9; }
    else if (bid < 1056) { src = Wf2;   off2 = OFF2_WF2;  csh = 9; }
    else if (bid < 1312) { src = W_out; off2 = OFF2_WOUT; csh = 9; }
    else                 { src = W_dec; off2 = OFF2_WDEC; csh = 6; }
    size_t e2 = e - off2;
    size_t kp = e2 >> csh;
    size_t c  = e2 & (((size_t)1 << csh) - 1);
    size_t C  = (size_t)1 << csh;
    dst[e] = packh2(src[(2 * kp) * C + c], src[(2 * kp + 1) * C + c]);
}

// ---------------------------------------------------------------------------
// fuse: Wfu = W_X @ We_x (fallback) and bias1 = b_X@We_x + b_emb (both paths)
// ---------------------------------------------------------------------------
__global__ __launch_bounds__(512) void fuse_kernel(
    const float* __restrict__ W_X, const float* __restrict__ W_emb,
    const float* __restrict__ b_X, const float* __restrict__ b_emb,
    unsigned* __restrict__ WfuP, float* __restrict__ bias1)
{
    const int bid = blockIdx.x;
    const int j   = threadIdx.x;
    if (bid < 32) {
        const int k0 = bid * 2;
        float a0 = 0.f, a1 = 0.f;
#pragma unroll 4
        for (int n = 0; n < HD; ++n) {
            float w = W_emb[(size_t)(HD + n) * HD + j];
            a0 = fmaf(W_X[(size_t)k0 * HD + n],       w, a0);
            a1 = fmaf(W_X[(size_t)(k0 + 1) * HD + n], w, a1);
        }
        WfuP[(bid << 9) + j] = packh2(a0, a1);
    } else {
        float a0 = 0.f;
#pragma unroll 4
        for (int n = 0; n < HD; ++n)
            a0 = fmaf(b_X[n], W_emb[(size_t)(HD + n) * HD + j], a0);
        bias1[j] = a0 + b_emb[j];
    }
}

// ---------------------------------------------------------------------------
// fp32 partial matvec
// ---------------------------------------------------------------------------
template<int K>
__device__ __forceinline__ void mv_part(const float* __restrict__ W,
                                        const float* src, float* part, int j)
{
    const int g = j >> 7, c = j & 127;
    const int kpg = K >> 2;
    const int k0 = g * kpg;
    const float4* __restrict__ W4 = (const float4*)W;
    float4 acc; acc.x = acc.y = acc.z = acc.w = 0.f;
#pragma unroll 2
    for (int k = k0; k < k0 + kpg; k += 4) {
        float4 a  = *(const float4*)(src + k);
        float4 w0 = W4[(size_t)(k + 0) * 128 + c];
        float4 w1 = W4[(size_t)(k + 1) * 128 + c];
        float4 w2 = W4[(size_t)(k + 2) * 128 + c];
        float4 w3 = W4[(size_t)(k + 3) * 128 + c];
        acc.x = fmaf(a.x, w0.x, acc.x); acc.y = fmaf(a.x, w0.y, acc.y);
        acc.z = fmaf(a.x, w0.z, acc.z); acc.w = fmaf(a.x, w0.w, acc.w);
        acc.x = fmaf(a.y, w1.x, acc.x); acc.y = fmaf(a.y, w1.y, acc.y);
        acc.z = fmaf(a.y, w1.z, acc.z); acc.w = fmaf(a.y, w1.w, acc.w);
        acc.x = fmaf(a.z, w2.x, acc.x); acc.y = fmaf(a.z, w2.y, acc.y);
        acc.z = fmaf(a.z, w2.z, acc.z); acc.w = fmaf(a.z, w2.w, acc.w);
        acc.x = fmaf(a.w, w3.x, acc.x); acc.y = fmaf(a.w, w3.y, acc.y);
        acc.z = fmaf(a.w, w3.z, acc.z); acc.w = fmaf(a.w, w3.w, acc.w);
    }
    *(float4*)(part + g * HD + 4 * c) = acc;
}
#define MV_REDUCE4(bias, j) ((bias)[j] + part[j] + part[HD + (j)] + part[2 * HD + (j)] + part[3 * HD + (j)])
#define MV_REDUCE8(bias, j) ((bias)[j] + ((part[j] + part[HD + (j)]) + (part[2 * HD + (j)] + part[3 * HD + (j)])) \
                           + ((part[4 * HD + (j)] + part[5 * HD + (j)]) + (part[6 * HD + (j)] + part[7 * HD + (j)])))

__global__ __launch_bounds__(512) void g_kernel(
    const float* __restrict__ times, const float* __restrict__ W_noise,
    const float* __restrict__ b_noise, const float* __restrict__ Wg1,
    const float* __restrict__ bg1, const float* __restrict__ Wg2,
    const float* __restrict__ bg2, float* __restrict__ gs)
{
    int t = blockIdx.x;
    int j = threadIdx.x;
    __shared__ float tt[HD];
    __shared__ float h[HD];
    __shared__ float part[4 * HD];
    float tv = times[t];
    tt[j] = tv * W_noise[j] + b_noise[j];
    __syncthreads();
    mv_part<HD>(Wg1, tt, part, j);
    __syncthreads();
    h[j] = lipswish(MV_REDUCE4(bg1, j));
    __syncthreads();
    mv_part<HD>(Wg2, h, part, j);
    __syncthreads();
    float dt = times[t + 1] - times[t];
    gs[t * HD + j] = MV_REDUCE4(bg2, j) * sqrtf(dt);
}

// ---------------------------------------------------------------------------
// small fp32 GEMM helpers (one-time precompute)
// ---------------------------------------------------------------------------
// C (512x512) = A (512x512, row stride 512) @ B (512x512). grid 512 x 512.
__global__ __launch_bounds__(512) void mmAB(const float* __restrict__ A,
                                            const float* __restrict__ B,
                                            float* __restrict__ C)
{
    int i = blockIdx.x, j = threadIdx.x;
    __shared__ float ar[HD];
    ar[j] = A[(size_t)i * HD + j];
    __syncthreads();
    float acc = 0.f;
#pragma unroll 4
    for (int n = 0; n < HD; ++n) acc = fmaf(ar[n], B[(size_t)n * HD + j], acc);
    C[(size_t)i * HD + j] = acc;
}

// C (64x512) = A (64x512) @ B (512x512). grid 64 x 512.
__global__ __launch_bounds__(512) void mm64(const float* __restrict__ A,
                                            const float* __restrict__ B,
                                            float* __restrict__ C)
{
    int i = blockIdx.x, j = threadIdx.x;
    __shared__ float ar[HD];
    ar[j] = A[(size_t)i * HD + j];
    __syncthreads();
    float acc = 0.f;
#pragma unroll 4
    for (int n = 0; n < HD; ++n) acc = fmaf(ar[n], B[(size_t)n * HD + j], acc);
    C[(size_t)i * HD + j] = acc;
}

// MdF (512x64) = H @ W_dec ; grid 512 x 64
__global__ __launch_bounds__(64) void mmHd(const float* __restrict__ H,
                                           const float* __restrict__ Wd,
                                           float* __restrict__ C)
{
    int i = blockIdx.x, c = threadIdx.x;
    __shared__ float hr[HD];
    for (int k = c; k < HD; k += 64) hr[k] = H[(size_t)i * HD + k];
    __syncthreads();
    float acc = 0.f;
#pragma unroll 4
    for (int n = 0; n < HD; ++n) acc = fmaf(hr[n], Wd[(size_t)n * 64 + c], acc);
    C[(size_t)i * 64 + c] = acc;
}

// McF (512x16, cols>=10 zero) = H @ W_cls ; grid 512 x 64
__global__ __launch_bounds__(64) void mmHc(const float* __restrict__ H,
                                           const float* __restrict__ Wc,
                                           float* __restrict__ C)
{
    int i = blockIdx.x, c = threadIdx.x;
    __shared__ float hr[HD];
    for (int k = c; k < HD; k += 64) hr[k] = H[(size_t)i * HD + k];
    __syncthreads();
    if (c < 16) {
        float acc = 0.f;
        if (c < NCLS) {
#pragma unroll 4
            for (int n = 0; n < HD; ++n) acc = fmaf(hr[n], Wc[(size_t)n * NCLS + c], acc);
        }
        C[(size_t)i * 16 + c] = acc;
    }
}

// vk1: bid0: c1 = bias1@Wf1 + bf1 ; bid1: h0 = bf2@W_out + b_out
__global__ __launch_bounds__(512) void vk1(const float* __restrict__ bias1,
    const float* __restrict__ Wf1, const float* __restrict__ bf1,
    const float* __restrict__ bf2, const float* __restrict__ W_out,
    const float* __restrict__ b_out, float* __restrict__ c1, float* __restrict__ h0)
{
    int j = threadIdx.x;
    __shared__ float vr[HD];
    if (blockIdx.x == 0) {
        vr[j] = bias1[j]; __syncthreads();
        float acc = 0.f;
#pragma unroll 4
        for (int n = 0; n < HD; ++n) acc = fmaf(vr[n], Wf1[(size_t)n * HD + j], acc);
        c1[j] = acc + bf1[j];
    } else {
        vr[j] = bf2[j]; __syncthreads();
        float acc = 0.f;
#pragma unroll 4
        for (int n = 0; n < HD; ++n) acc = fmaf(vr[n], W_out[(size_t)n * HD + j], acc);
        h0[j] = acc + b_out[j];
    }
}

// vk2: bid0: m0 = h0@G ; bid1: md0 = h0@W_dec, mc0 = h0@W_cls (padded 16)
__global__ __launch_bounds__(512) void vk2(const float* __restrict__ h0,
    const float* __restrict__ G, const float* __restrict__ Wd,
    const float* __restrict__ Wc, float* __restrict__ m0,
    float* __restrict__ md0, float* __restrict__ mc0)
{
    int j = threadIdx.x;
    __shared__ float vr[HD];
    vr[j] = h0[j]; __syncthreads();
    if (blockIdx.x == 0) {
        float acc = 0.f;
#pragma unroll 4
        for (int n = 0; n < HD; ++n) acc = fmaf(vr[n], G[(size_t)n * HD + j], acc);
        m0[j] = acc;
    } else {
        if (j < 64) {
            float acc = 0.f;
#pragma unroll 4
            for (int n = 0; n < HD; ++n) acc = fmaf(vr[n], Wd[(size_t)n * 64 + j], acc);
            md0[j] = acc;
        } else if (j < 80) {
            int c = j - 64;
            float acc = 0.f;
            if (c < NCLS) {
                for (int n = 0; n < HD; ++n) acc = fmaf(vr[n], Wc[(size_t)n * NCLS + c], acc);
            }
            mc0[c] = acc;
        }
    }
}

// packall: fp32 -> half2-pair packs for all new-path matrices. grid 592 x 512.
__global__ __launch_bounds__(512) void packall(
    const float* __restrict__ Mf, const float* __restrict__ Gf,
    const float* __restrict__ F1f, const float* __restrict__ MdF,
    const float* __restrict__ McF, const float* __restrict__ Wc,
    unsigned* __restrict__ M2, unsigned* __restrict__ G2,
    unsigned* __restrict__ F1P, unsigned* __restrict__ MdP,
    unsigned* __restrict__ McP, unsigned* __restrict__ Wc16)
{
    int bid = blockIdx.x, j = threadIdx.x;
    if (bid < 256) {
        int kp = bid;
        M2[(kp << 9) + j] = packh2(Mf[(size_t)(2 * kp) * HD + j], Mf[(size_t)(2 * kp + 1) * HD + j]);
    } else if (bid < 512) {
        int kp = bid - 256;
        G2[(kp << 9) + j] = packh2(Gf[(size_t)(2 * kp) * HD + j], Gf[(size_t)(2 * kp + 1) * HD + j]);
    } else if (bid < 544) {
        int kp = bid - 512;
        F1P[(kp << 9) + j] = packh2(F1f[(size_t)(2 * kp) * HD + j], F1f[(size_t)(2 * kp + 1) * HD + j]);
    } else if (bid < 576) {
        int e = (bid - 544) * 512 + j;
        int kp = e >> 6, c = e & 63;
        MdP[e] = packh2(MdF[(size_t)(2 * kp) * 64 + c], MdF[(size_t)(2 * kp + 1) * 64 + c]);
    } else if (bid < 584) {
        int e = (bid - 576) * 512 + j;
        int kp = e >> 4, c = e & 15;
        McP[e] = packh2(McF[(size_t)(2 * kp) * 16 + c], McF[(size_t)(2 * kp + 1) * 16 + c]);
    } else {
        int e = (bid - 584) * 512 + j;
        int kp = e >> 4, c = e & 15;
        float v0 = (c < NCLS) ? Wc[(size_t)(2 * kp) * NCLS + c] : 0.f;
        float v1 = (c < NCLS) ? Wc[(size_t)(2 * kp + 1) * NCLS + c] : 0.f;
        Wc16[e] = packh2(v0, v1);
    }
}

// ---------------------------------------------------------------------------
// eg: E1 = dW@G (half out), Ed = dW@W_dec (f32), Ec = dW@W_cls16 (f32)
// dW[r,n] = gs[t,n]*noise[r,n], r = t*B+b. grid 1592 x 512, 32 rows/block.
// ---------------------------------------------------------------------------
__global__ __launch_bounds__(512) void eg_kernel(
    const float* __restrict__ noise, const float* __restrict__ gs,
    const unsigned* __restrict__ G2, const unsigned* __restrict__ Wd2,
    const unsigned* __restrict__ Wc16,
    __half* __restrict__ E1h, float* __restrict__ Edf, float* __restrict__ Ecf)
{
    const int r0 = blockIdx.x * 32;
    const int t  = r0 >> 8;
    const int j  = threadIdx.x;
    __shared__ unsigned dWH[32 * 256];   // [rr*256 + kp]

#pragma unroll
    for (int i = 0; i < 16; ++i) {
        int e = i * 512 + j;
        int rr = e >> 8, kp = e & 255;
        float2 nz = *(const float2*)(noise + (size_t)(r0 + rr) * HD + 2 * kp);
        float2 gv = *(const float2*)(gs + (size_t)t * HD + 2 * kp);
        dWH[rr * 256 + kp] = packh2(nz.x * gv.x, nz.y * gv.y);
    }
    __syncthreads();

    // E1: 4 row-groups (8 rows) x 128 col-quads
    {
        const int rg = j >> 7, cq = j & 127;
        float acc[8][4];
#pragma unroll
        for (int s = 0; s < 8; ++s)
#pragma unroll
            for (int c = 0; c < 4; ++c) acc[s][c] = 0.f;
#pragma unroll 2
        for (int kp = 0; kp < 256; ++kp) {
            uint4 w = *(const uint4*)(G2 + ((size_t)kp << 9) + (cq << 2));
#pragma unroll
            for (int s = 0; s < 8; ++s) {
                unsigned a = dWH[(rg * 8 + s) * 256 + kp];
                acc[s][0] = fdot2u(a, w.x, acc[s][0]);
                acc[s][1] = fdot2u(a, w.y, acc[s][1]);
                acc[s][2] = fdot2u(a, w.z, acc[s][2]);
                acc[s][3] = fdot2u(a, w.w, acc[s][3]);
            }
        }
#pragma unroll
        for (int s = 0; s < 8; ++s) {
            size_t row = r0 + rg * 8 + s;
            *(unsigned*)(E1h + row * HD + 4 * cq)     = packh2(acc[s][0], acc[s][1]);
            *(unsigned*)(E1h + row * HD + 4 * cq + 2) = packh2(acc[s][2], acc[s][3]);
        }
    }
    // Ed: 8 row-groups (4 rows) x 64 cols
    {
        const int rgrp = j >> 6, c = j & 63;
        float ad[4] = {0.f, 0.f, 0.f, 0.f};
#pragma unroll 4
        for (int kp = 0; kp < 256; ++kp) {
            unsigned wv = Wd2[(kp << 6) + c];
#pragma unroll
            for (int s = 0; s < 4; ++s)
                ad[s] = fdot2u(dWH[(rgrp * 4 + s) * 256 + kp], wv, ad[s]);
        }
#pragma unroll
        for (int s = 0; s < 4; ++s)
            Edf[(size_t)(r0 + rgrp * 4 + s) * 64 + c] = ad[s];
    }
    // Ec: 32 rows x 16 cols
    {
        const int rr = j >> 4, c = j & 15;
        float ac = 0.f;
#pragma unroll 4
        for (int kp = 0; kp < 256; ++kp)
            ac = fdot2u(dWH[rr * 256 + kp], Wc16[(kp << 4) + c], ac);
        Ecf[(size_t)(r0 + rr) * 16 + c] = ac;
    }
}

// ---------------------------------------------------------------------------
// dot2 matvec, 512 cols: 8 kp-groups x 64 col-octets (shared by both scans)
// ---------------------------------------------------------------------------
template<int KP>
__device__ __forceinline__ void mv_dot2(const unsigned* __restrict__ W2,
                                        const unsigned* actH, float* part, int j)
{
    const int g = j >> 6, o8 = (j & 63) << 3;
    constexpr int kpg = KP / 8;
    const int kp0 = g * kpg;
    float acc[8];
#pragma unroll
    for (int i = 0; i < 8; ++i) acc[i] = 0.f;
#pragma unroll 8
    for (int kp = kp0; kp < kp0 + kpg; ++kp) {
        unsigned ap = actH[kp];
        uint4 w0 = *(const uint4*)(W2 + ((size_t)kp << 9) + o8);
        uint4 w1 = *(const uint4*)(W2 + ((size_t)kp << 9) + o8 + 4);
        acc[0] = fdot2u(ap, w0.x, acc[0]);
        acc[1] = fdot2u(ap, w0.y, acc[1]);
        acc[2] = fdot2u(ap, w0.z, acc[2]);
        acc[3] = fdot2u(ap, w0.w, acc[3]);
        acc[4] = fdot2u(ap, w1.x, acc[4]);
        acc[5] = fdot2u(ap, w1.y, acc[5]);
        acc[6] = fdot2u(ap, w1.z, acc[6]);
        acc[7] = fdot2u(ap, w1.w, acc[7]);
    }
    float* pb = part + (g << 9) + o8;
    *(float4*)(pb)     = make_float4(acc[0], acc[1], acc[2], acc[3]);
    *(float4*)(pb + 4) = make_float4(acc[4], acc[5], acc[6], acc[7]);
}

// ---------------------------------------------------------------------------
// NEW scan: state conjugated into s-space. Streams only M (0.5 MB/step).
// grid = B x 512.
// ---------------------------------------------------------------------------
__global__ __launch_bounds__(512) void scan_fast(
    const float* __restrict__ coeffs, const float* __restrict__ times,
    const int* __restrict__ mask,
    const unsigned* __restrict__ M2G, const unsigned* __restrict__ F1P,
    const unsigned* __restrict__ MdP, const unsigned* __restrict__ McP,
    const float* __restrict__ c1G, const float* __restrict__ m0G,
    const float* __restrict__ md0G, const float* __restrict__ mc0G,
    const float* __restrict__ GfG,
    const float* __restrict__ W_init, const float* __restrict__ b_init,
    const float* __restrict__ W_dec, const float* __restrict__ b_dec,
    const float* __restrict__ W_cls, const float* __restrict__ b_cls,
    const __half* __restrict__ E1h, const float* __restrict__ Edf,
    const float* __restrict__ Ecf,
    float* __restrict__ out)
{
    const int b = blockIdx.x;
    const int j = threadIdx.x;

    __shared__ __align__(16) unsigned F1L[32 * HD];     // 64 KB
    __shared__ __align__(16) unsigned MdL[32 * HD];     // 64 KB (256 kp x 64)
    __shared__ __align__(16) float    part[8 * HD];     // 16 KB
    __shared__ __align__(16) float    y0L[HD];
    __shared__ __align__(16) float    c1L[HD];
    __shared__ __align__(16) float    m0L[HD];
    __shared__ __align__(16) float    partd[512];
    __shared__ __align__(16) float    partw[256];
    __shared__ __align__(16) unsigned actH[HD / 2];
    __shared__ float    tl[TT];
    __shared__ float    md0L[64], bdecL[64];
    __shared__ float    vL[64];
    __shared__ float    avec[DIN];
    __shared__ unsigned avecH[DIN / 2];
    __shared__ float    mc0L[16], wL[16], wfinL[16];
    __shared__ int      lidx_s;

    if (j < TT) tl[j] = times[j];
#pragma unroll
    for (int i = 0; i < 32; ++i) F1L[(i << 9) + j] = F1P[(i << 9) + j];
#pragma unroll
    for (int i = 0; i < 32; ++i) MdL[(i << 9) + j] = MdP[(i << 9) + j];
    c1L[j] = c1G[j];
    m0L[j] = m0G[j];
    if (j < 64) { md0L[j] = md0G[j]; bdecL[j] = b_dec[j]; }
    if (j < 16) { mc0L[j] = mc0G[j]; wL[j] = 0.f; wfinL[j] = 0.f; }

    // per-row length
    {
        int m = 0;
        for (int t = j; t < TT; t += 512) m += mask[b * TT + t];
        part[j] = (float)m;
        __syncthreads();
        for (int s = 256; s > 0; s >>= 1) {
            if (j < s) part[j] += part[j + s];
            __syncthreads();
        }
        if (j == 0) lidx_s = (int)part[0] - 1;
        __syncthreads();
    }
    const int lidx = lidx_s;

    // y0 = a0@W_init + b_init
    if (j < DIN / 4)
        ((float4*)avec)[j] = ((const float4*)(coeffs + (size_t)b * (TT - 1) * 4 * DIN))[j];
    __syncthreads();
    mv_part<DIN>(W_init, avec, part, j);
    __syncthreads();
    y0L[j] = MV_REDUCE4(b_init, j);
    __syncthreads();

    // q0 = y0@G (fp32), v0 = y0@W_dec, w0 = y0@W_cls
    mv_part<HD>(GfG, y0L, part, j);
    if (j < 64) {
        float acc = 0.f;
#pragma unroll 4
        for (int n = 0; n < HD; ++n) acc = fmaf(y0L[n], W_dec[(size_t)n * 64 + j], acc);
        vL[j] = acc;
        out[((size_t)b * TT) * DOUT + j] = acc + b_dec[j];
    } else if (j >= 64 && j < 64 + NCLS) {
        int c = j - 64;
        float acc = 0.f;
#pragma unroll 4
        for (int n = 0; n < HD; ++n) acc = fmaf(y0L[n], W_cls[(size_t)n * NCLS + c], acc);
        wL[c] = acc;
    }
    __syncthreads();
    float q = part[j] + part[HD + j] + part[2 * HD + j] + part[3 * HD + j];
    if (j < 16 && lidx == 0) wfinL[j] = wL[j];
    __syncthreads();

    // ---- main scan: 3 barriers/step, one 0.5 MB streamed matrix ----
    for (int t = 0; t < TT - 1; ++t) {
        if (j < 32) {
            float2 a2 = ((const float2*)(coeffs + ((size_t)b * (TT - 1) + t) * 4 * DIN))[j];
            avecH[j] = packh2(a2.x, a2.y);
        }
        __syncthreads();   // S1
        {
            float s = q + c1L[j];
#pragma unroll
            for (int kp = 0; kp < 32; ++kp)
                s = fdot2u(avecH[kp], F1L[(kp << 9) + j], s);
            float z2 = lipswish(s);
            pack_store(z2, actH, j);
        }
        __syncthreads();   // S2
        mv_dot2<256>(M2G, actH, part, j);
        {
            int g = j >> 6, c = j & 63;
            float dacc = 0.f;
#pragma unroll 8
            for (int kp = g * 32; kp < g * 32 + 32; ++kp)
                dacc = fdot2u(actH[kp], MdL[(kp << 6) + c], dacc);
            partd[(g << 6) + c] = dacc;
        }
        if (j < 256) {
            int gw = j >> 4, cw = j & 15;
            float wacc = 0.f;
#pragma unroll
            for (int i2 = 0; i2 < 16; ++i2) {
                int kp = gw * 16 + i2;
                wacc = fdot2u(actH[kp], McP[(kp << 4) + cw], wacc);
            }
            partw[(gw << 4) + cw] = wacc;
        }
        __syncthreads();   // S3
        {
            float dtv = tl[t + 1] - tl[t];
            size_t rbase = (size_t)t * BB + b;
            float red = ((part[j] + part[HD + j]) + (part[2 * HD + j] + part[3 * HD + j]))
                      + ((part[4 * HD + j] + part[5 * HD + j]) + (part[6 * HD + j] + part[7 * HD + j]));
            q = q + dtv * (red + m0L[j]) + __half2float(E1h[rbase * HD + j]);
            if (j < 64) {
                float dv = 0.f;
#pragma unroll
                for (int g = 0; g < 8; ++g) dv += partd[(g << 6) + j];
                float vn = vL[j] + dtv * (dv + md0L[j]) + Edf[rbase * 64 + j];
                vL[j] = vn;
                out[((size_t)b * TT + t + 1) * DOUT + j] = vn + bdecL[j];
            }
            if (j < 16) {
                float dw = 0.f;
#pragma unroll
                for (int g = 0; g < 16; ++g) dw += partw[(g << 4) + j];
                float wn = wL[j] + dtv * (dw + mc0L[j]) + Ecf[rbase * 16 + j];
                wL[j] = wn;
                if (t + 1 == lidx) wfinL[j] = wn;
            }
        }
    }
    __syncthreads();
    if (j < NCLS)
        out[(size_t)BB * TT * DOUT + b * NCLS + j] = wfinL[j] + b_cls[j];
}

// ---------------------------------------------------------------------------
// FALLBACK scan (verified R3 kernel, used when ws is too small)
// ---------------------------------------------------------------------------
__device__ __forceinline__ void decode_store_d2(const unsigned* __restrict__ Wd2,
    const float* __restrict__ b_dec, const unsigned* yH, float* part, float* dscr,
    int j, float* __restrict__ outp)
{
    const int g = j >> 3, o8 = (j & 7) << 3;
    const int kp0 = g << 2;
    float acc[8];
#pragma unroll
    for (int i = 0; i < 8; ++i) acc[i] = 0.f;
#pragma unroll
    for (int kp = kp0; kp < kp0 + 4; ++kp) {
        unsigned ap = yH[kp];
        uint4 w0 = *(const uint4*)(Wd2 + ((size_t)kp << 6) + o8);
        uint4 w1 = *(const uint4*)(Wd2 + ((size_t)kp << 6) + o8 + 4);
        acc[0] = fdot2u(ap, w0.x, acc[0]);
        acc[1] = fdot2u(ap, w0.y, acc[1]);
        acc[2] = fdot2u(ap, w0.z, acc[2]);
        acc[3] = fdot2u(ap, w0.w, acc[3]);
        acc[4] = fdot2u(ap, w1.x, acc[4]);
        acc[5] = fdot2u(ap, w1.y, acc[5]);
        acc[6] = fdot2u(ap, w1.z, acc[6]);
        acc[7] = fdot2u(ap, w1.w, acc[7]);
    }
    float* pb = part + (g << 6) + o8;
    *(float4*)(pb)     = make_float4(acc[0], acc[1], acc[2], acc[3]);
    *(float4*)(pb + 4) = make_float4(acc[4], acc[5], acc[6], acc[7]);
    __syncthreads();
    {
        int o2 = j >> 6, col = j & 63;
        float s = 0.f;
#pragma unroll
        for (int i = 0; i < 8; ++i) s += part[((o2 << 3) + i) * 64 + col];
        dscr[(o2 << 6) + col] = s;
    }
    __syncthreads();
    if (j < DOUT) {
        float s = b_dec[j];
#pragma unroll
        for (int i = 0; i < 8; ++i) s += dscr[(i << 6) + j];
        outp[j] = s;
    }
}

__global__ __launch_bounds__(512) void scan_fb(
    const float* __restrict__ coeffs, const float* __restrict__ times,
    const float* __restrict__ noise, const float* __restrict__ bias1,
    const float* __restrict__ bf1, const float* __restrict__ bf2,
    const float* __restrict__ b_out,
    const float* __restrict__ W_init, const float* __restrict__ b_init,
    const float* __restrict__ b_dec,
    const float* __restrict__ W_cls, const float* __restrict__ b_cls,
    const int* __restrict__ mask, const float* __restrict__ gs,
    const unsigned* __restrict__ W2, const unsigned* __restrict__ WfuG,
    float* __restrict__ out)
{
    const int b = blockIdx.x;
    const int j = threadIdx.x;

    const unsigned* __restrict__ W_emb_2 = W2 + OFF2_WEMB;
    const unsigned* __restrict__ Wf1_2   = W2 + OFF2_WF1;
    const unsigned* __restrict__ Wf2_2   = W2 + OFF2_WF2;
    const unsigned* __restrict__ W_out_2 = W2 + OFF2_WOUT;
    const unsigned* __restrict__ W_dec_2 = W2 + OFF2_WDEC;

    __shared__ float    yF[HD];
    __shared__ unsigned yH[HD / 2];
    __shared__ unsigned actAH[HD / 2];
    __shared__ unsigned actBH[HD / 2];
    __shared__ unsigned avecH[DIN / 2];
    __shared__ unsigned WfuL[32 * HD];
    __shared__ float    part[8 * HD];
    __shared__ float    dscr[HD];
    __shared__ float    avec[DIN];
    __shared__ float    zfin[HD];
    __shared__ float    tl[TT];
    __shared__ int      last_idx_s;

    if (j < TT) tl[j] = times[j];
#pragma unroll
    for (int i = 0; i < 32; ++i) WfuL[i * 512 + j] = WfuG[i * 512 + j];
    {
        int m = 0;
        for (int t = j; t < TT; t += 512) m += mask[b * TT + t];
        part[j] = (float)m;
        __syncthreads();
        for (int s = 256; s > 0; s >>= 1) {
            if (j < s) part[j] += part[j + s];
            __syncthreads();
        }
        if (j == 0) last_idx_s = (int)part[0] - 1;
        __syncthreads();
    }
    const int last_idx = last_idx_s;

    if (j < DIN / 4)
        ((float4*)avec)[j] = ((const float4*)(coeffs + (size_t)b * (TT - 1) * 4 * DIN))[j];
    __syncthreads();
    mv_part<DIN>(W_init, avec, part, j);
    __syncthreads();
    {
        float y = MV_REDUCE4(b_init, j);
        yF[j] = y;
        pack_store(y, yH, j);
        if (last_idx == 0) zfin[j] = y;
    }
    __syncthreads();
    decode_store_d2(W_dec_2, b_dec, yH, part, dscr, j, out + ((size_t)b * TT) * DOUT);

    for (int t = 0; t < TT - 1; ++t) {
        if (j < DIN / 2) {
            float2 a2 = ((const float2*)(coeffs + ((size_t)b * (TT - 1) + t) * 4 * DIN))[j];
            avecH[j] = packh2(a2.x, a2.y);
        }
        __syncthreads();
        mv_dot2<HD / 2>(W_emb_2, yH, part, j);
        __syncthreads();
        {
            float s = MV_REDUCE8(bias1, j);
#pragma unroll
            for (int kp = 0; kp < 32; ++kp)
                s = fdot2u(avecH[kp], WfuL[(kp << 9) + j], s);
            pack_store(s, actAH, j);
        }
        __syncthreads();
        mv_dot2<HD / 2>(Wf1_2, actAH, part, j);
        __syncthreads();
        pack_store(lipswish(MV_REDUCE8(bf1, j)), actBH, j);
        __syncthreads();
        mv_dot2<HD / 2>(Wf2_2, actBH, part, j);
        __syncthreads();
        pack_store(MV_REDUCE8(bf2, j), actAH, j);
        __syncthreads();
        mv_dot2<HD / 2>(W_out_2, actAH, part, j);
        __syncthreads();
        {
            float dr = MV_REDUCE8(b_out, j);
            float dtv = tl[t + 1] - tl[t];
            float yn = yF[j] + dr * dtv
                     + gs[(size_t)t * HD + j] * noise[((size_t)t * BB + b) * HD + j];
            yF[j] = yn;
            pack_store(yn, yH, j);
            if (t + 1 == last_idx) zfin[j] = yn;
        }
        __syncthreads();
        decode_store_d2(W_dec_2, b_dec, yH, part, dscr, j,
                        out + ((size_t)b * TT + (t + 1)) * DOUT);
    }
    __syncthreads();
    {
        int c = j & 15, seg = j >> 4;
        float p = 0.f;
        if (c < NCLS) {
#pragma unroll
            for (int k = seg * 16; k < seg * 16 + 16; ++k)
                p = fmaf(zfin[k], W_cls[k * NCLS + c], p);
        }
        part[j] = p;
        __syncthreads();
        if (j < NCLS) {
            float s = b_cls[j];
#pragma unroll
            for (int sg = 0; sg < 32; ++sg) s += part[sg * 16 + j];
            out[(size_t)BB * TT * DOUT + b * NCLS + j] = s;
        }
    }
}

extern "C" void kernel_launch(void* const* d_in, const int* in_sizes, int n_in,
                              void* d_out, int out_size, void* d_ws, size_t ws_size,
                              hipStream_t stream)
{
    const float* coeffs  = (const float*)d_in[0];
    const float* times   = (const float*)d_in[1];
    const float* noise   = (const float*)d_in[2];
    const float* W_X     = (const float*)d_in[3];
    const float* b_X     = (const float*)d_in[4];
    const float* W_emb   = (const float*)d_in[5];
    const float* b_emb   = (const float*)d_in[6];
    const float* Wf1     = (const float*)d_in[7];
    const float* bf1     = (const float*)d_in[8];
    const float* Wf2     = (const float*)d_in[9];
    const float* bf2     = (const float*)d_in[10];
    const float* W_out   = (const float*)d_in[11];
    const float* b_out   = (const float*)d_in[12];
    const float* W_noise = (const float*)d_in[13];
    const float* b_noise = (const float*)d_in[14];
    const float* Wg1     = (const float*)d_in[15];
    const float* bg1     = (const float*)d_in[16];
    const float* Wg2     = (const float*)d_in[17];
    const float* bg2     = (const float*)d_in[18];
    const float* W_init  = (const float*)d_in[19];
    const float* b_init  = (const float*)d_in[20];
    const float* W_dec   = (const float*)d_in[21];
    const float* b_dec   = (const float*)d_in[22];
    const float* W_cls   = (const float*)d_in[23];
    const float* b_cls   = (const float*)d_in[24];
    const int*   mask    = (const int*)d_in[25];

    char* ws = (char*)d_ws;
    float*    gs    = (float*)ws;
    unsigned* W2    = (unsigned*)(ws + GS_BYTES);
    unsigned* WfuP  = W2 + NPACK;
    float*    bias1 = (float*)(W2 + NPACK + NFU);
    float*    out   = (float*)d_out;

    cvt_kernel<<<dim3(NPACK / 512), dim3(512), 0, stream>>>(
        W_X, W_emb, Wf1, Wf2, W_out, W_dec, W2);

    fuse_kernel<<<dim3(33), dim3(512), 0, stream>>>(
        W_X, W_emb, b_X, b_emb, WfuP, bias1);

    g_kernel<<<dim3(TT - 1), dim3(HD), 0, stream>>>(
        times, W_noise, b_noise, Wg1, bg1, Wg2, bg2, gs);

    if (ws_size >= WS_NEED) {
        float*    Gf   = (float*)(ws + OFF_GF);
        float*    Hf   = (float*)(ws + OFF_HF);
        float*    Mf   = (float*)(ws + OFF_MF);
        float*    T64f = (float*)(ws + OFF_T64);
        float*    F1f  = (float*)(ws + OFF_F1F);
        float*    MdF  = (float*)(ws + OFF_MDF);
        float*    McF  = (float*)(ws + OFF_MCF);
        float*    c1   = (float*)(ws + OFF_C1);
        float*    h0   = (float*)(ws + OFF_H0);
        float*    m0   = (float*)(ws + OFF_M0);
        float*    md0  = (float*)(ws + OFF_MD0);
        float*    mc0  = (float*)(ws + OFF_MC0);
        unsigned* M2   = (unsigned*)(ws + OFF_M2);
        unsigned* G2   = (unsigned*)(ws + OFF_G2);
        unsigned* F1P  = (unsigned*)(ws + OFF_F1P);
        unsigned* MdP  = (unsigned*)(ws + OFF_MDP);
        unsigned* McP  = (unsigned*)(ws + OFF_MCP);
        unsigned* Wc16 = (unsigned*)(ws + OFF_WC16);
        __half*   E1h  = (__half*)(ws + OFF_E1H);
        float*    Edf  = (float*)(ws + OFF_EDF);
        float*    Ecf  = (float*)(ws + OFF_ECF);
        unsigned* Wd2  = W2 + OFF2_WDEC;

        // G = We_y@Wf1 ; H = Wf2@W_out ; Mf = H@G
        mmAB<<<dim3(512), dim3(512), 0, stream>>>(W_emb, Wf1, Gf);
        mmAB<<<dim3(512), dim3(512), 0, stream>>>(Wf2, W_out, Hf);
        mmAB<<<dim3(512), dim3(512), 0, stream>>>(Hf, Gf, Mf);
        // F1 = (W_X@We_x)@Wf1
        mm64<<<dim3(64), dim3(512), 0, stream>>>(W_X, W_emb + (size_t)HD * HD, T64f);
        mm64<<<dim3(64), dim3(512), 0, stream>>>(T64f, Wf1, F1f);
        // Md = H@W_dec ; Mc = H@W_cls
        mmHd<<<dim3(512), dim3(64), 0, stream>>>(Hf, W_dec, MdF);
        mmHc<<<dim3(512), dim3(64), 0, stream>>>(Hf, W_cls, McF);
        // c1, h0, m0, md0, mc0
        vk1<<<dim3(2), dim3(512), 0, stream>>>(bias1, Wf1, bf1, bf2, W_out, b_out, c1, h0);
        vk2<<<dim3(2), dim3(512), 0, stream>>>(h0, Gf, W_dec, W_cls, m0, md0, mc0);
        // packs
        packall<<<dim3(592), dim3(512), 0, stream>>>(Mf, Gf, F1f, MdF, McF, W_cls,
                                                     M2, G2, F1P, MdP, McP, Wc16);
        // E tables
        eg_kernel<<<dim3((TT - 1) * BB / 32), dim3(512), 0, stream>>>(
            noise, gs, G2, Wd2, Wc16, E1h, Edf, Ecf);
        // scan
        scan_fast<<<dim3(BB), dim3(512), 0, stream>>>(
            coeffs, times, mask, M2, F1P, MdP, McP, c1, m0, md0, mc0,
            Gf, W_init, b_init, W_dec, b_dec, W_cls, b_cls,
            E1h, Edf, Ecf, out);
    } else {
        scan_fb<<<dim3(BB), dim3(512), 0, stream>>>(
            coeffs, times, noise, bias1, bf1, bf2, b_out,
            W_init, b_init, b_dec, W_cls, b_cls, mask, gs, W2, WfuP, out);
    }
}